// Round 1
// baseline (590.643 us; speedup 1.0000x reference)
//
#include <hip/hip_runtime.h>

#define N_NODES 50000
#define N_EDGES 400000
#define FEATS   128
#define LAT     64
#define IN_CH   192   // LAT + FEATS
#define HID     512
#define M_TILE  32

static inline int cdiv(int a, int b) { return (a + b - 1) / b; }

// ---------------- degree / normalization ----------------

__global__ void k_init_deg(float* __restrict__ deg) {
    int i = blockIdx.x * blockDim.x + threadIdx.x;
    if (i < N_NODES) deg[i] = 1.0f;   // self-loop
}

__global__ void k_count_deg(const int* __restrict__ col, float* __restrict__ deg) {
    int e = blockIdx.x * blockDim.x + threadIdx.x;
    if (e < N_EDGES) atomicAdd(&deg[col[e]], 1.0f);
}

__global__ void k_dinv(float* __restrict__ deg) {
    int i = blockIdx.x * blockDim.x + threadIdx.x;
    if (i < N_NODES) deg[i] = rsqrtf(deg[i]);   // deg >= 1 always
}

// ---------------- layer-1 aggregation of latent (192-dim) ----------------
// agg[i][f] = dinv[i]^2 * latent[i][f]  (self-loop term; also inits agg)
__global__ void k_agg_self(const float* __restrict__ uY, const float* __restrict__ X,
                           const float* __restrict__ dinv, float* __restrict__ agg) {
    int idx = blockIdx.x * blockDim.x + threadIdx.x;   // float4 index
    if (idx >= N_NODES * (IN_CH / 4)) return;
    int i = idx / (IN_CH / 4);
    int q = idx % (IN_CH / 4);
    float d = dinv[i]; float d2 = d * d;
    const float4* uY4 = (const float4*)uY;
    const float4* X4  = (const float4*)X;
    float4 v = (q < LAT / 4) ? uY4[i * (LAT / 4) + q]
                             : X4[i * (FEATS / 4) + (q - LAT / 4)];
    float4 o; o.x = d2 * v.x; o.y = d2 * v.y; o.z = d2 * v.z; o.w = d2 * v.w;
    ((float4*)agg)[idx] = o;
}

// one wave per edge: agg[c][*] += dinv[r]*dinv[c] * latent[r][*]
__global__ void k_agg_edges(const int* __restrict__ ei,
                            const float* __restrict__ uY, const float* __restrict__ X,
                            const float* __restrict__ dinv, float* __restrict__ agg) {
    int e = blockIdx.x * (blockDim.x >> 6) + (threadIdx.x >> 6);
    int lane = threadIdx.x & 63;
    if (e >= N_EDGES) return;
    int r = ei[e];
    int c = ei[N_EDGES + e];
    float norm = dinv[r] * dinv[c];
    atomicAdd(&agg[c * IN_CH + lane],       norm * uY[r * LAT + lane]);
    atomicAdd(&agg[c * IN_CH + 64 + lane],  norm * X[r * FEATS + lane]);
    atomicAdd(&agg[c * IN_CH + 128 + lane], norm * X[r * FEATS + 64 + lane]);
}

// ---------------- fused GEMM: y_pre = relu(agg @ W1 + b1) @ W2 ----------------
// block = 256 threads, M_TILE = 32 rows. Thread t owns cols n0=t, n1=t+256.
__global__ __launch_bounds__(256) void
k_gemm_fused(const float* __restrict__ agg, const float* __restrict__ W1,
             const float* __restrict__ b1, const float* __restrict__ W2,
             float* __restrict__ y_pre) {
    __shared__ float As[M_TILE * IN_CH];       // 24.5 KB
    __shared__ float red[4 * M_TILE * 2];      // 1 KB: [wave][m][j]

    int t  = threadIdx.x;
    int m0 = blockIdx.x * M_TILE;

    // stage A tile (float4, coalesced); zero-fill rows past N
    float4* Asv = (float4*)As;
    const float4* aggv = (const float4*)agg;
    for (int idx = t; idx < M_TILE * (IN_CH / 4); idx += 256) {
        int m = idx / (IN_CH / 4);
        int q = idx % (IN_CH / 4);
        float4 v = make_float4(0.f, 0.f, 0.f, 0.f);
        int row = m0 + m;
        if (row < N_NODES) v = aggv[row * (IN_CH / 4) + q];
        Asv[idx] = v;
    }
    __syncthreads();

    int n0 = t, n1 = t + 256;
    float acc0[M_TILE], acc1[M_TILE];
#pragma unroll
    for (int m = 0; m < M_TILE; ++m) { acc0[m] = 0.f; acc1[m] = 0.f; }

    for (int k = 0; k < IN_CH; k += 4) {
        float w00 = W1[(k + 0) * HID + n0];
        float w01 = W1[(k + 1) * HID + n0];
        float w02 = W1[(k + 2) * HID + n0];
        float w03 = W1[(k + 3) * HID + n0];
        float w10 = W1[(k + 0) * HID + n1];
        float w11 = W1[(k + 1) * HID + n1];
        float w12 = W1[(k + 2) * HID + n1];
        float w13 = W1[(k + 3) * HID + n1];
#pragma unroll
        for (int m = 0; m < M_TILE; ++m) {
            float4 a = Asv[(m * IN_CH + k) >> 2];   // broadcast b128 read
            acc0[m] = fmaf(a.w, w03, fmaf(a.z, w02, fmaf(a.y, w01, fmaf(a.x, w00, acc0[m]))));
            acc1[m] = fmaf(a.w, w13, fmaf(a.z, w12, fmaf(a.y, w11, fmaf(a.x, w10, acc1[m]))));
        }
    }

    // epilogue: relu + bias, project to 2 outputs, reduce across 512 cols
    float b1n0 = b1[n0], b1n1 = b1[n1];
    float w2a0 = W2[n0 * 2 + 0], w2a1 = W2[n0 * 2 + 1];
    float w2b0 = W2[n1 * 2 + 0], w2b1 = W2[n1 * 2 + 1];
    int lane = t & 63, wid = t >> 6;

#pragma unroll
    for (int m = 0; m < M_TILE; ++m) {
        float h0 = fmaxf(acc0[m] + b1n0, 0.f);
        float h1 = fmaxf(acc1[m] + b1n1, 0.f);
        float c0 = fmaf(h0, w2a0, h1 * w2b0);
        float c1 = fmaf(h0, w2a1, h1 * w2b1);
#pragma unroll
        for (int off = 32; off; off >>= 1) {
            c0 += __shfl_down(c0, off);
            c1 += __shfl_down(c1, off);
        }
        if (lane == 0) {
            red[wid * (M_TILE * 2) + m * 2 + 0] = c0;
            red[wid * (M_TILE * 2) + m * 2 + 1] = c1;
        }
    }
    __syncthreads();
    if (t < M_TILE * 2) {
        float s = red[t] + red[M_TILE * 2 + t] + red[2 * M_TILE * 2 + t] + red[3 * M_TILE * 2 + t];
        int m = t >> 1, j = t & 1;
        int row = m0 + m;
        if (row < N_NODES) y_pre[row * 2 + j] = s;
    }
}

// ---------------- layer-2 aggregation (2-dim) + softmax ----------------

__global__ void k_y_self(const float* __restrict__ y_pre, const float* __restrict__ dinv,
                         float* __restrict__ y_agg) {
    int i = blockIdx.x * blockDim.x + threadIdx.x;
    if (i >= N_NODES) return;
    float d = dinv[i]; float d2 = d * d;
    y_agg[i * 2 + 0] = d2 * y_pre[i * 2 + 0];
    y_agg[i * 2 + 1] = d2 * y_pre[i * 2 + 1];
}

__global__ void k_y_edges(const int* __restrict__ ei, const float* __restrict__ y_pre,
                          const float* __restrict__ dinv, float* __restrict__ y_agg) {
    int e = blockIdx.x * blockDim.x + threadIdx.x;
    if (e >= N_EDGES) return;
    int r = ei[e];
    int c = ei[N_EDGES + e];
    float norm = dinv[r] * dinv[c];
    atomicAdd(&y_agg[c * 2 + 0], norm * y_pre[r * 2 + 0]);
    atomicAdd(&y_agg[c * 2 + 1], norm * y_pre[r * 2 + 1]);
}

__global__ void k_softmax(const float* __restrict__ y_agg, const float* __restrict__ b2,
                          float* __restrict__ out) {
    int i = blockIdx.x * blockDim.x + threadIdx.x;
    if (i >= N_NODES) return;
    float a = y_agg[i * 2 + 0] + b2[0];
    float b = y_agg[i * 2 + 1] + b2[1];
    float mx = fmaxf(a, b);
    float e0 = expf(a - mx);
    float e1 = expf(b - mx);
    float inv = 1.0f / (e0 + e1);
    out[i * 2 + 0] = e0 * inv;
    out[i * 2 + 1] = e1 * inv;
}

// ---------------- launch ----------------

extern "C" void kernel_launch(void* const* d_in, const int* in_sizes, int n_in,
                              void* d_out, int out_size, void* d_ws, size_t ws_size,
                              hipStream_t stream) {
    const int*   ei = (const int*)d_in[0];
    const float* X  = (const float*)d_in[1];
    const float* uY = (const float*)d_in[2];
    const float* W1 = (const float*)d_in[3];
    const float* b1 = (const float*)d_in[4];
    const float* W2 = (const float*)d_in[5];
    const float* b2 = (const float*)d_in[6];
    float* out = (float*)d_out;

    // workspace carve (256B aligned)
    char* ws = (char*)d_ws;
    auto carve = [&](size_t bytes) {
        char* p = ws;
        ws += (bytes + 255) & ~size_t(255);
        return p;
    };
    float* dinv  = (float*)carve(N_NODES * sizeof(float));
    float* agg   = (float*)carve((size_t)N_NODES * IN_CH * sizeof(float));
    float* y_pre = (float*)carve((size_t)N_NODES * 2 * sizeof(float));
    float* y_agg = (float*)carve((size_t)N_NODES * 2 * sizeof(float));

    k_init_deg <<<cdiv(N_NODES, 256), 256, 0, stream>>>(dinv);
    k_count_deg<<<cdiv(N_EDGES, 256), 256, 0, stream>>>(ei + N_EDGES, dinv);
    k_dinv     <<<cdiv(N_NODES, 256), 256, 0, stream>>>(dinv);

    k_agg_self <<<cdiv(N_NODES * (IN_CH / 4), 256), 256, 0, stream>>>(uY, X, dinv, agg);
    k_agg_edges<<<cdiv(N_EDGES * 64, 256), 256, 0, stream>>>(ei, uY, X, dinv, agg);

    k_gemm_fused<<<cdiv(N_NODES, M_TILE), 256, 0, stream>>>(agg, W1, b1, W2, y_pre);

    k_y_self   <<<cdiv(N_NODES, 256), 256, 0, stream>>>(y_pre, dinv, y_agg);
    k_y_edges  <<<cdiv(N_EDGES, 256), 256, 0, stream>>>(ei, y_pre, dinv, y_agg);
    k_softmax  <<<cdiv(N_NODES, 256), 256, 0, stream>>>(y_agg, b2, out);
}

// Round 2
// 474.724 us; speedup vs baseline: 1.2442x; 1.2442x over previous
//
#include <hip/hip_runtime.h>

#define N_NODES 50000
#define N_EDGES 400000
#define FEATS   128
#define LAT     64
#define IN_CH   192   // LAT + FEATS
#define HID     512
#define M_TILE  32
#define SCAN_T  1024

static inline int cdiv(int a, int b) { return (a + b - 1) / b; }

// ---------------- CSR build ----------------

__global__ void k_zero_cnt(int* __restrict__ cnt) {
    int i = blockIdx.x * blockDim.x + threadIdx.x;
    if (i < N_NODES) cnt[i] = 0;
}

__global__ void k_count(const int* __restrict__ col, int* __restrict__ cnt) {
    int e = blockIdx.x * blockDim.x + threadIdx.x;
    if (e < N_EDGES) atomicAdd(&cnt[col[e]], 1);
}

__global__ void k_dinv(const int* __restrict__ cnt, float* __restrict__ dinv) {
    int i = blockIdx.x * blockDim.x + threadIdx.x;
    if (i < N_NODES) dinv[i] = rsqrtf((float)(cnt[i] + 1));   // +1 self-loop
}

// single-block exclusive scan of cnt[0..N) -> row_start & cursor
__global__ __launch_bounds__(SCAN_T) void
k_scan(const int* __restrict__ cnt, int* __restrict__ row_start, int* __restrict__ cursor) {
    __shared__ int sums[SCAN_T];
    const int CHUNK = (N_NODES + SCAN_T - 1) / SCAN_T;   // 49
    int t  = threadIdx.x;
    int lo = t * CHUNK;
    int hi = min(lo + CHUNK, N_NODES);
    int s = 0;
    for (int i = lo; i < hi; ++i) s += cnt[i];
    sums[t] = s;
    __syncthreads();
    // inclusive Hillis-Steele scan
    for (int off = 1; off < SCAN_T; off <<= 1) {
        int add = (t >= off) ? sums[t - off] : 0;
        __syncthreads();
        sums[t] += add;
        __syncthreads();
    }
    int base = sums[t] - s;   // exclusive prefix for this chunk
    for (int i = lo; i < hi; ++i) {
        row_start[i] = base;
        cursor[i]    = base;
        base += cnt[i];
    }
    if (t == 0) row_start[N_NODES] = N_EDGES;
}

__global__ void k_scatter(const int* __restrict__ ei, const float* __restrict__ dinv,
                          int* __restrict__ cursor,
                          int* __restrict__ csr_src, float* __restrict__ csr_w) {
    int e = blockIdx.x * blockDim.x + threadIdx.x;
    if (e >= N_EDGES) return;
    int r = ei[e];
    int c = ei[N_EDGES + e];
    int pos = atomicAdd(&cursor[c], 1);
    csr_src[pos] = r;
    csr_w[pos]   = dinv[r];
}

// ---------------- layer-1 aggregation: one wave per node ----------------
// agg[i] = dinv[i] * ( dinv[i]*latent[i] + sum_j dinv[r_j]*latent[r_j] )
__global__ __launch_bounds__(256) void
k_gather_agg(const int* __restrict__ row_start, const int* __restrict__ csr_src,
             const float* __restrict__ csr_w, const float* __restrict__ dinv,
             const float* __restrict__ uY, const float* __restrict__ X,
             float* __restrict__ agg) {
    int w    = blockIdx.x * 4 + (threadIdx.x >> 6);
    int lane = threadIdx.x & 63;
    if (w >= N_NODES) return;
    float di = dinv[w];
    float acc0 = di * uY[w * LAT + lane];
    float acc1 = di * X[w * FEATS + lane];
    float acc2 = di * X[w * FEATS + 64 + lane];
    int jlo = row_start[w], jhi = row_start[w + 1];
    for (int j = jlo; j < jhi; ++j) {
        int   r  = csr_src[j];
        float wt = csr_w[j];
        acc0 = fmaf(wt, uY[r * LAT + lane],        acc0);
        acc1 = fmaf(wt, X[r * FEATS + lane],       acc1);
        acc2 = fmaf(wt, X[r * FEATS + 64 + lane],  acc2);
    }
    agg[w * IN_CH + lane]       = di * acc0;
    agg[w * IN_CH + 64 + lane]  = di * acc1;
    agg[w * IN_CH + 128 + lane] = di * acc2;
}

// ---------------- fused GEMM: y_pre = relu(agg @ W1 + b1) @ W2 ----------------
__global__ __launch_bounds__(256) void
k_gemm_fused(const float* __restrict__ agg, const float* __restrict__ W1,
             const float* __restrict__ b1, const float* __restrict__ W2,
             float* __restrict__ y_pre) {
    __shared__ float As[M_TILE * IN_CH];       // 24.5 KB
    __shared__ float red[4 * M_TILE * 2];      // 1 KB

    int t  = threadIdx.x;
    int m0 = blockIdx.x * M_TILE;

    float4* Asv = (float4*)As;
    const float4* aggv = (const float4*)agg;
    for (int idx = t; idx < M_TILE * (IN_CH / 4); idx += 256) {
        int m = idx / (IN_CH / 4);
        int q = idx % (IN_CH / 4);
        float4 v = make_float4(0.f, 0.f, 0.f, 0.f);
        int row = m0 + m;
        if (row < N_NODES) v = aggv[row * (IN_CH / 4) + q];
        Asv[idx] = v;
    }
    __syncthreads();

    int n0 = t, n1 = t + 256;
    float acc0[M_TILE], acc1[M_TILE];
#pragma unroll
    for (int m = 0; m < M_TILE; ++m) { acc0[m] = 0.f; acc1[m] = 0.f; }

    for (int k = 0; k < IN_CH; k += 4) {
        float w00 = W1[(k + 0) * HID + n0];
        float w01 = W1[(k + 1) * HID + n0];
        float w02 = W1[(k + 2) * HID + n0];
        float w03 = W1[(k + 3) * HID + n0];
        float w10 = W1[(k + 0) * HID + n1];
        float w11 = W1[(k + 1) * HID + n1];
        float w12 = W1[(k + 2) * HID + n1];
        float w13 = W1[(k + 3) * HID + n1];
#pragma unroll
        for (int m = 0; m < M_TILE; ++m) {
            float4 a = Asv[(m * IN_CH + k) >> 2];
            acc0[m] = fmaf(a.w, w03, fmaf(a.z, w02, fmaf(a.y, w01, fmaf(a.x, w00, acc0[m]))));
            acc1[m] = fmaf(a.w, w13, fmaf(a.z, w12, fmaf(a.y, w11, fmaf(a.x, w10, acc1[m]))));
        }
    }

    float b1n0 = b1[n0], b1n1 = b1[n1];
    float w2a0 = W2[n0 * 2 + 0], w2a1 = W2[n0 * 2 + 1];
    float w2b0 = W2[n1 * 2 + 0], w2b1 = W2[n1 * 2 + 1];
    int lane = t & 63, wid = t >> 6;

#pragma unroll
    for (int m = 0; m < M_TILE; ++m) {
        float h0 = fmaxf(acc0[m] + b1n0, 0.f);
        float h1 = fmaxf(acc1[m] + b1n1, 0.f);
        float c0 = fmaf(h0, w2a0, h1 * w2b0);
        float c1 = fmaf(h0, w2a1, h1 * w2b1);
#pragma unroll
        for (int off = 32; off; off >>= 1) {
            c0 += __shfl_down(c0, off);
            c1 += __shfl_down(c1, off);
        }
        if (lane == 0) {
            red[wid * (M_TILE * 2) + m * 2 + 0] = c0;
            red[wid * (M_TILE * 2) + m * 2 + 1] = c1;
        }
    }
    __syncthreads();
    if (t < M_TILE * 2) {
        float s = red[t] + red[M_TILE * 2 + t] + red[2 * M_TILE * 2 + t] + red[3 * M_TILE * 2 + t];
        int m = t >> 1, j = t & 1;
        int row = m0 + m;
        if (row < N_NODES) y_pre[row * 2 + j] = s;
    }
}

// ---------------- layer-2 gather + bias + softmax, one thread per node ----------------
__global__ void k_gather_y(const int* __restrict__ row_start, const int* __restrict__ csr_src,
                           const float* __restrict__ csr_w, const float* __restrict__ dinv,
                           const float* __restrict__ y_pre, const float* __restrict__ b2,
                           float* __restrict__ out) {
    int i = blockIdx.x * blockDim.x + threadIdx.x;
    if (i >= N_NODES) return;
    float di = dinv[i];
    float a0 = di * y_pre[i * 2 + 0];
    float a1 = di * y_pre[i * 2 + 1];
    int jlo = row_start[i], jhi = row_start[i + 1];
    for (int j = jlo; j < jhi; ++j) {
        int   r  = csr_src[j];
        float wt = csr_w[j];
        a0 = fmaf(wt, y_pre[r * 2 + 0], a0);
        a1 = fmaf(wt, y_pre[r * 2 + 1], a1);
    }
    float ya = di * a0 + b2[0];
    float yb = di * a1 + b2[1];
    float mx = fmaxf(ya, yb);
    float e0 = expf(ya - mx);
    float e1 = expf(yb - mx);
    float inv = 1.0f / (e0 + e1);
    out[i * 2 + 0] = e0 * inv;
    out[i * 2 + 1] = e1 * inv;
}

// ---------------- launch ----------------

extern "C" void kernel_launch(void* const* d_in, const int* in_sizes, int n_in,
                              void* d_out, int out_size, void* d_ws, size_t ws_size,
                              hipStream_t stream) {
    const int*   ei = (const int*)d_in[0];
    const float* X  = (const float*)d_in[1];
    const float* uY = (const float*)d_in[2];
    const float* W1 = (const float*)d_in[3];
    const float* b1 = (const float*)d_in[4];
    const float* W2 = (const float*)d_in[5];
    const float* b2 = (const float*)d_in[6];
    float* out = (float*)d_out;

    char* ws = (char*)d_ws;
    auto carve = [&](size_t bytes) {
        char* p = ws;
        ws += (bytes + 255) & ~size_t(255);
        return p;
    };
    int*   cnt       = (int*)carve(N_NODES * sizeof(int));
    int*   row_start = (int*)carve((N_NODES + 1) * sizeof(int));
    int*   cursor    = (int*)carve(N_NODES * sizeof(int));
    int*   csr_src   = (int*)carve((size_t)N_EDGES * sizeof(int));
    float* csr_w     = (float*)carve((size_t)N_EDGES * sizeof(float));
    float* dinv      = (float*)carve(N_NODES * sizeof(float));
    float* agg       = (float*)carve((size_t)N_NODES * IN_CH * sizeof(float));
    float* y_pre     = (float*)carve((size_t)N_NODES * 2 * sizeof(float));

    k_zero_cnt<<<cdiv(N_NODES, 256), 256, 0, stream>>>(cnt);
    k_count   <<<cdiv(N_EDGES, 256), 256, 0, stream>>>(ei + N_EDGES, cnt);
    k_dinv    <<<cdiv(N_NODES, 256), 256, 0, stream>>>(cnt, dinv);
    k_scan    <<<1, SCAN_T, 0, stream>>>(cnt, row_start, cursor);
    k_scatter <<<cdiv(N_EDGES, 256), 256, 0, stream>>>(ei, dinv, cursor, csr_src, csr_w);

    k_gather_agg<<<cdiv(N_NODES, 4), 256, 0, stream>>>(row_start, csr_src, csr_w, dinv, uY, X, agg);

    k_gemm_fused<<<cdiv(N_NODES, M_TILE), 256, 0, stream>>>(agg, W1, b1, W2, y_pre);

    k_gather_y<<<cdiv(N_NODES, 256), 256, 0, stream>>>(row_start, csr_src, csr_w, dinv, y_pre, b2, out);
}

// Round 3
// 331.603 us; speedup vs baseline: 1.7812x; 1.4316x over previous
//
#include <hip/hip_runtime.h>

#define N_NODES 50000
#define N_EDGES 400000
#define FEATS   128
#define LAT     64
#define IN_CH   192   // LAT + FEATS
#define HID     512
#define MB      64    // GEMM rows per block
#define SCAN_T  1024

typedef __attribute__((ext_vector_type(8))) short bf16x8;
typedef __attribute__((ext_vector_type(4))) float f32x4;

static inline int cdiv(int a, int b) { return (a + b - 1) / b; }

__device__ __forceinline__ unsigned short f2bf(float f) {
    unsigned int u = __float_as_uint(f);
    u = (u + 0x7fffu + ((u >> 16) & 1u)) >> 16;   // round-to-nearest-even
    return (unsigned short)u;
}
__device__ __forceinline__ float bf2f(unsigned int h) {
    return __uint_as_float(h << 16);
}

// ---------------- CSR build ----------------

__global__ void k_zero_cnt(int* __restrict__ cnt) {
    int i = blockIdx.x * blockDim.x + threadIdx.x;
    if (i < N_NODES) cnt[i] = 0;
}

__global__ void k_count(const int* __restrict__ col, int* __restrict__ cnt) {
    int e = blockIdx.x * blockDim.x + threadIdx.x;
    if (e < N_EDGES) atomicAdd(&cnt[col[e]], 1);
}

__global__ void k_dinv(const int* __restrict__ cnt, float* __restrict__ dinv) {
    int i = blockIdx.x * blockDim.x + threadIdx.x;
    if (i < N_NODES) dinv[i] = rsqrtf((float)(cnt[i] + 1));   // +1 self-loop
}

__global__ __launch_bounds__(SCAN_T) void
k_scan(const int* __restrict__ cnt, int* __restrict__ row_start, int* __restrict__ cursor) {
    __shared__ int sums[SCAN_T];
    const int CHUNK = (N_NODES + SCAN_T - 1) / SCAN_T;   // 49
    int t  = threadIdx.x;
    int lo = t * CHUNK;
    int hi = min(lo + CHUNK, N_NODES);
    int s = 0;
    for (int i = lo; i < hi; ++i) s += cnt[i];
    sums[t] = s;
    __syncthreads();
    for (int off = 1; off < SCAN_T; off <<= 1) {
        int add = (t >= off) ? sums[t - off] : 0;
        __syncthreads();
        sums[t] += add;
        __syncthreads();
    }
    int base = sums[t] - s;
    for (int i = lo; i < hi; ++i) {
        row_start[i] = base;
        cursor[i]    = base;
        base += cnt[i];
    }
    if (t == 0) row_start[N_NODES] = N_EDGES;
}

__global__ void k_scatter(const int* __restrict__ ei, const float* __restrict__ dinv,
                          int* __restrict__ cursor,
                          int* __restrict__ csr_src, float* __restrict__ csr_w) {
    int e = blockIdx.x * blockDim.x + threadIdx.x;
    if (e >= N_EDGES) return;
    int r = ei[e];
    int c = ei[N_EDGES + e];
    int pos = atomicAdd(&cursor[c], 1);
    csr_src[pos] = r;
    csr_w[pos]   = dinv[r];
}

// ---------------- precision conversions ----------------
// latent_bf16[i][0:64) = uY[i], [64:192) = X[i]; row-major packed bf16
__global__ void k_cvt_latent(const float* __restrict__ uY, const float* __restrict__ X,
                             unsigned short* __restrict__ latent) {
    int idx = blockIdx.x * blockDim.x + threadIdx.x;   // float4 index, 48/row
    if (idx >= N_NODES * 48) return;
    int i = idx / 48, q = idx % 48;
    const float4* uY4 = (const float4*)uY;
    const float4* X4  = (const float4*)X;
    float4 v = (q < LAT / 4) ? uY4[i * (LAT / 4) + q]
                             : X4[i * (FEATS / 4) + (q - LAT / 4)];
    uint2 o;
    o.x = (unsigned int)f2bf(v.x) | ((unsigned int)f2bf(v.y) << 16);
    o.y = (unsigned int)f2bf(v.z) | ((unsigned int)f2bf(v.w) << 16);
    ((uint2*)latent)[idx] = o;
}

// retile W1 [192,512] fp32 -> fragment-ordered bf16:
// W1f[(((ntile*6 + kc)*64 + q*16 + nn)*8 + j)] = W1[kc*32+q*8+j][ntile*16+nn]
__global__ void k_w1_tile(const float* __restrict__ W1, unsigned short* __restrict__ W1f) {
    int idx = blockIdx.x * blockDim.x + threadIdx.x;
    if (idx >= IN_CH * HID) return;
    int k = idx / HID, n = idx % HID;       // coalesced read over n
    int ntile = n >> 4, nn = n & 15;
    int kc = k >> 5, q = (k >> 3) & 3, j = k & 7;
    int dst = (((ntile * 6 + kc) * 64 + q * 16 + nn) << 3) + j;
    W1f[dst] = f2bf(W1[idx]);
}

// ---------------- layer-1 gather (bf16 in, bf16 out) ----------------
__global__ __launch_bounds__(256) void
k_gather_agg(const int* __restrict__ row_start, const int* __restrict__ csr_src,
             const float* __restrict__ csr_w, const float* __restrict__ dinv,
             const unsigned short* __restrict__ latent, unsigned short* __restrict__ agg) {
    int w    = blockIdx.x * 4 + (threadIdx.x >> 6);
    int lane = threadIdx.x & 63;
    if (w >= N_NODES) return;
    float di = dinv[w];
    const unsigned int* Lw = (const unsigned int*)(latent + (size_t)w * IN_CH);
    unsigned int u = Lw[lane];
    float a0 = di * bf2f(u & 0xffffu);                              // feat 2l
    float a1 = di * bf2f(u >> 16);                                  // feat 2l+1
    float a2 = di * bf2f((unsigned int)((const unsigned short*)Lw)[128 + lane]); // feat 128+l
    int jlo = row_start[w], jhi = row_start[w + 1];
    for (int j = jlo; j < jhi; ++j) {
        int   r  = csr_src[j];
        float wt = csr_w[j];
        const unsigned int* Lr = (const unsigned int*)(latent + (size_t)r * IN_CH);
        unsigned int v = Lr[lane];
        unsigned short v2 = ((const unsigned short*)Lr)[128 + lane];
        a0 = fmaf(wt, bf2f(v & 0xffffu), a0);
        a1 = fmaf(wt, bf2f(v >> 16), a1);
        a2 = fmaf(wt, bf2f((unsigned int)v2), a2);
    }
    unsigned int* Aw = (unsigned int*)(agg + (size_t)w * IN_CH);
    Aw[lane] = (unsigned int)f2bf(di * a0) | ((unsigned int)f2bf(di * a1) << 16);
    ((unsigned short*)Aw)[128 + lane] = f2bf(di * a2);
}

// ---------------- MFMA GEMM: y_pre = relu(agg @ W1 + b1) @ W2 ----------------
// block: 256 thr (4 waves), 64 rows x 512 cols x K=192. Wave w: cols [w*128, w*128+128).
__global__ __launch_bounds__(256, 2) void
k_gemm_mfma(const unsigned short* __restrict__ agg, const unsigned short* __restrict__ W1f,
            const float* __restrict__ b1, const float* __restrict__ W2,
            float* __restrict__ y_pre) {
    __shared__ unsigned short Af[MB * IN_CH];   // 24 KB, fragment-ordered
    __shared__ float red[4][MB][2];             // 2 KB

    int t  = threadIdx.x;
    int m0 = blockIdx.x * MB;

    // stage A tile: chunk = 16B = 8 bf16. row-major src -> fragment-ordered LDS
    {
        const uint4* src = (const uint4*)agg;   // 24 chunks per row
        for (int idx = t; idx < MB * 24; idx += 256) {
            int row = idx / 24, c = idx % 24;
            int g = m0 + row;
            uint4 v = make_uint4(0u, 0u, 0u, 0u);
            if (g < N_NODES) v = src[(size_t)g * 24 + c];
            int mt = row >> 4, m = row & 15, kc = c >> 2, q = c & 3;
            ((uint4*)Af)[(mt * 6 + kc) * 64 + q * 16 + m] = v;
        }
    }
    __syncthreads();

    int wid = t >> 6, lane = t & 63;
    int nl = lane & 15, q = lane >> 4;

    float b1v[8], w2a[8], w2b[8];
#pragma unroll
    for (int nt = 0; nt < 8; ++nt) {
        int n = wid * 128 + nt * 16 + nl;
        b1v[nt] = b1[n];
        w2a[nt] = W2[n * 2 + 0];
        w2b[nt] = W2[n * 2 + 1];
    }

    f32x4 acc[4][8];
#pragma unroll
    for (int mt = 0; mt < 4; ++mt)
#pragma unroll
        for (int nt = 0; nt < 8; ++nt) acc[mt][nt] = (f32x4){0.f, 0.f, 0.f, 0.f};

    const bf16x8* Afv = (const bf16x8*)Af;
    const bf16x8* Bv  = (const bf16x8*)W1f;
#pragma unroll
    for (int kc = 0; kc < 6; ++kc) {
        bf16x8 a[4];
#pragma unroll
        for (int mt = 0; mt < 4; ++mt) a[mt] = Afv[(mt * 6 + kc) * 64 + lane];
#pragma unroll
        for (int nt = 0; nt < 8; ++nt) {
            bf16x8 b = Bv[((wid * 8 + nt) * 6 + kc) * 64 + lane];
#pragma unroll
            for (int mt = 0; mt < 4; ++mt)
                acc[mt][nt] = __builtin_amdgcn_mfma_f32_16x16x32_bf16(a[mt], b, acc[mt][nt], 0, 0, 0);
        }
    }

    // epilogue: h = relu(C + b1); y += h * W2 ; reduce over N
#pragma unroll
    for (int mt = 0; mt < 4; ++mt) {
#pragma unroll
        for (int r = 0; r < 4; ++r) {
            float p0 = 0.f, p1 = 0.f;
#pragma unroll
            for (int nt = 0; nt < 8; ++nt) {
                float h = fmaxf(acc[mt][nt][r] + b1v[nt], 0.f);
                p0 = fmaf(h, w2a[nt], p0);
                p1 = fmaf(h, w2b[nt], p1);
            }
#pragma unroll
            for (int off = 1; off < 16; off <<= 1) {
                p0 += __shfl_xor(p0, off);
                p1 += __shfl_xor(p1, off);
            }
            if (nl == 0) {
                int row = mt * 16 + q * 4 + r;
                red[wid][row][0] = p0;
                red[wid][row][1] = p1;
            }
        }
    }
    __syncthreads();
    if (t < MB * 2) {
        int row = t >> 1, j = t & 1;
        float s = red[0][row][j] + red[1][row][j] + red[2][row][j] + red[3][row][j];
        int g = m0 + row;
        if (g < N_NODES) y_pre[g * 2 + j] = s;
    }
}

// ---------------- layer-2 gather + bias + softmax ----------------
__global__ void k_gather_y(const int* __restrict__ row_start, const int* __restrict__ csr_src,
                           const float* __restrict__ csr_w, const float* __restrict__ dinv,
                           const float* __restrict__ y_pre, const float* __restrict__ b2,
                           float* __restrict__ out) {
    int i = blockIdx.x * blockDim.x + threadIdx.x;
    if (i >= N_NODES) return;
    float di = dinv[i];
    float a0 = di * y_pre[i * 2 + 0];
    float a1 = di * y_pre[i * 2 + 1];
    int jlo = row_start[i], jhi = row_start[i + 1];
    for (int j = jlo; j < jhi; ++j) {
        int   r  = csr_src[j];
        float wt = csr_w[j];
        a0 = fmaf(wt, y_pre[r * 2 + 0], a0);
        a1 = fmaf(wt, y_pre[r * 2 + 1], a1);
    }
    float ya = di * a0 + b2[0];
    float yb = di * a1 + b2[1];
    float mx = fmaxf(ya, yb);
    float e0 = expf(ya - mx);
    float e1 = expf(yb - mx);
    float inv = 1.0f / (e0 + e1);
    out[i * 2 + 0] = e0 * inv;
    out[i * 2 + 1] = e1 * inv;
}

// ---------------- launch ----------------

extern "C" void kernel_launch(void* const* d_in, const int* in_sizes, int n_in,
                              void* d_out, int out_size, void* d_ws, size_t ws_size,
                              hipStream_t stream) {
    const int*   ei = (const int*)d_in[0];
    const float* X  = (const float*)d_in[1];
    const float* uY = (const float*)d_in[2];
    const float* W1 = (const float*)d_in[3];
    const float* b1 = (const float*)d_in[4];
    const float* W2 = (const float*)d_in[5];
    const float* b2 = (const float*)d_in[6];
    float* out = (float*)d_out;

    char* ws = (char*)d_ws;
    auto carve = [&](size_t bytes) {
        char* p = ws;
        ws += (bytes + 255) & ~size_t(255);
        return p;
    };
    int*   cnt       = (int*)carve(N_NODES * sizeof(int));
    int*   row_start = (int*)carve((N_NODES + 1) * sizeof(int));
    int*   cursor    = (int*)carve(N_NODES * sizeof(int));
    int*   csr_src   = (int*)carve((size_t)N_EDGES * sizeof(int));
    float* csr_w     = (float*)carve((size_t)N_EDGES * sizeof(float));
    float* dinv      = (float*)carve(N_NODES * sizeof(float));
    unsigned short* latent = (unsigned short*)carve((size_t)N_NODES * IN_CH * 2);
    unsigned short* aggb   = (unsigned short*)carve((size_t)N_NODES * IN_CH * 2);
    unsigned short* W1f    = (unsigned short*)carve((size_t)IN_CH * HID * 2);
    float* y_pre     = (float*)carve((size_t)N_NODES * 2 * sizeof(float));

    k_zero_cnt  <<<cdiv(N_NODES, 256), 256, 0, stream>>>(cnt);
    k_count     <<<cdiv(N_EDGES, 256), 256, 0, stream>>>(ei + N_EDGES, cnt);
    k_dinv      <<<cdiv(N_NODES, 256), 256, 0, stream>>>(cnt, dinv);
    k_scan      <<<1, SCAN_T, 0, stream>>>(cnt, row_start, cursor);
    k_scatter   <<<cdiv(N_EDGES, 256), 256, 0, stream>>>(ei, dinv, cursor, csr_src, csr_w);

    k_cvt_latent<<<cdiv(N_NODES * 48, 256), 256, 0, stream>>>(uY, X, latent);
    k_w1_tile   <<<cdiv(IN_CH * HID, 256), 256, 0, stream>>>(W1, W1f);

    k_gather_agg<<<cdiv(N_NODES, 4), 256, 0, stream>>>(row_start, csr_src, csr_w, dinv, latent, aggb);

    k_gemm_mfma <<<cdiv(N_NODES, MB), 256, 0, stream>>>(aggb, W1f, b1, W2, y_pre);

    k_gather_y  <<<cdiv(N_NODES, 256), 256, 0, stream>>>(row_start, csr_src, csr_w, dinv, y_pre, b2, out);
}

// Round 4
// 233.029 us; speedup vs baseline: 2.5346x; 1.4230x over previous
//
#include <hip/hip_runtime.h>

#define N_NODES 50000
#define N_EDGES 400000
#define FEATS   128
#define LAT     64
#define IN_CH   192   // LAT + FEATS
#define HID     512
#define MB      64    // GEMM rows per block
#define NB      196   // cdiv(N_NODES, 256)

typedef __attribute__((ext_vector_type(8))) short bf16x8;
typedef __attribute__((ext_vector_type(4))) float f32x4;

static inline int cdiv(int a, int b) { return (a + b - 1) / b; }

__device__ __forceinline__ unsigned short f2bf(float f) {
    unsigned int u = __float_as_uint(f);
    u = (u + 0x7fffu + ((u >> 16) & 1u)) >> 16;   // round-to-nearest-even
    return (unsigned short)u;
}
__device__ __forceinline__ float bf2f(unsigned int h) {
    return __uint_as_float(h << 16);
}

// ---------------- CSR build ----------------

__global__ void k_zero_cnt(int* __restrict__ cnt) {
    int i = blockIdx.x * blockDim.x + threadIdx.x;
    if (i < N_NODES) cnt[i] = 0;
}

__global__ void k_count(const int* __restrict__ col, int* __restrict__ cnt) {
    int e = blockIdx.x * blockDim.x + threadIdx.x;
    if (e < N_EDGES) atomicAdd(&cnt[col[e]], 1);
}

// phase 1: per-block sums
__global__ __launch_bounds__(256) void
k_block_reduce(const int* __restrict__ cnt, int* __restrict__ bsum) {
    __shared__ int wsums[4];
    int i = blockIdx.x * 256 + threadIdx.x;
    int v = (i < N_NODES) ? cnt[i] : 0;
#pragma unroll
    for (int off = 32; off; off >>= 1) v += __shfl_down(v, off);
    if ((threadIdx.x & 63) == 0) wsums[threadIdx.x >> 6] = v;
    __syncthreads();
    if (threadIdx.x == 0) bsum[blockIdx.x] = wsums[0] + wsums[1] + wsums[2] + wsums[3];
}

// phase 2: scan the 196 block sums (single tiny block)
__global__ __launch_bounds__(256) void
k_scan_bsums(const int* __restrict__ bsum, int* __restrict__ bex) {
    __shared__ int wsums[4];
    int t = threadIdx.x, lane = t & 63, wid = t >> 6;
    int v = (t < NB) ? bsum[t] : 0;
    int x = v;
#pragma unroll
    for (int off = 1; off < 64; off <<= 1) {
        int y = __shfl_up(x, off);
        if (lane >= off) x += y;
    }
    if (lane == 63) wsums[wid] = x;
    __syncthreads();
    int wo = 0;
    for (int w = 0; w < wid; ++w) wo += wsums[w];
    if (t < NB) bex[t] = wo + x - v;   // exclusive prefix
}

// phase 3: per-block exclusive scan + block base; fuses dinv
__global__ __launch_bounds__(256) void
k_block_scan(const int* __restrict__ cnt, const int* __restrict__ bex,
             int* __restrict__ row_start, int* __restrict__ cursor,
             float* __restrict__ dinv) {
    __shared__ int wsums[4];
    int t = threadIdx.x, lane = t & 63, wid = t >> 6;
    int i = blockIdx.x * 256 + t;
    int v = (i < N_NODES) ? cnt[i] : 0;
    int x = v;
#pragma unroll
    for (int off = 1; off < 64; off <<= 1) {
        int y = __shfl_up(x, off);
        if (lane >= off) x += y;
    }
    if (lane == 63) wsums[wid] = x;
    __syncthreads();
    int wo = 0;
    for (int w = 0; w < wid; ++w) wo += wsums[w];
    int ex = bex[blockIdx.x] + wo + x - v;
    if (i < N_NODES) {
        row_start[i] = ex;
        cursor[i]    = ex;
        dinv[i]      = rsqrtf((float)(v + 1));   // +1 self-loop
    }
    if (blockIdx.x == 0 && t == 0) row_start[N_NODES] = N_EDGES;
}

__global__ void k_scatter(const int* __restrict__ ei, const float* __restrict__ dinv,
                          int* __restrict__ cursor,
                          int* __restrict__ csr_src, float* __restrict__ csr_w) {
    int e = blockIdx.x * blockDim.x + threadIdx.x;
    if (e >= N_EDGES) return;
    int r = ei[e];
    int c = ei[N_EDGES + e];
    int pos = atomicAdd(&cursor[c], 1);
    csr_src[pos] = r;
    csr_w[pos]   = dinv[r];
}

// ---------------- precision conversions ----------------
__global__ void k_cvt_latent(const float* __restrict__ uY, const float* __restrict__ X,
                             unsigned short* __restrict__ latent) {
    int idx = blockIdx.x * blockDim.x + threadIdx.x;   // float4 index, 48/row
    if (idx >= N_NODES * 48) return;
    int i = idx / 48, q = idx % 48;
    const float4* uY4 = (const float4*)uY;
    const float4* X4  = (const float4*)X;
    float4 v = (q < LAT / 4) ? uY4[i * (LAT / 4) + q]
                             : X4[i * (FEATS / 4) + (q - LAT / 4)];
    uint2 o;
    o.x = (unsigned int)f2bf(v.x) | ((unsigned int)f2bf(v.y) << 16);
    o.y = (unsigned int)f2bf(v.z) | ((unsigned int)f2bf(v.w) << 16);
    ((uint2*)latent)[idx] = o;
}

// retile W1 [192,512] fp32 -> fragment-ordered bf16
__global__ void k_w1_tile(const float* __restrict__ W1, unsigned short* __restrict__ W1f) {
    int idx = blockIdx.x * blockDim.x + threadIdx.x;
    if (idx >= IN_CH * HID) return;
    int k = idx / HID, n = idx % HID;       // coalesced read over n
    int ntile = n >> 4, nn = n & 15;
    int kc = k >> 5, q = (k >> 3) & 3, j = k & 7;
    int dst = (((ntile * 6 + kc) * 64 + q * 16 + nn) << 3) + j;
    W1f[dst] = f2bf(W1[idx]);
}

// ---------------- layer-1 gather (bf16 in, bf16 out) ----------------
__global__ __launch_bounds__(256) void
k_gather_agg(const int* __restrict__ row_start, const int* __restrict__ csr_src,
             const float* __restrict__ csr_w, const float* __restrict__ dinv,
             const unsigned short* __restrict__ latent, unsigned short* __restrict__ agg) {
    int w    = blockIdx.x * 4 + (threadIdx.x >> 6);
    int lane = threadIdx.x & 63;
    if (w >= N_NODES) return;
    float di = dinv[w];
    const unsigned int* Lw = (const unsigned int*)(latent + (size_t)w * IN_CH);
    unsigned int u = Lw[lane];
    float a0 = di * bf2f(u & 0xffffu);
    float a1 = di * bf2f(u >> 16);
    float a2 = di * bf2f((unsigned int)((const unsigned short*)Lw)[128 + lane]);
    int jlo = row_start[w], jhi = row_start[w + 1];
    for (int j = jlo; j < jhi; ++j) {
        int   r  = csr_src[j];
        float wt = csr_w[j];
        const unsigned int* Lr = (const unsigned int*)(latent + (size_t)r * IN_CH);
        unsigned int v = Lr[lane];
        unsigned short v2 = ((const unsigned short*)Lr)[128 + lane];
        a0 = fmaf(wt, bf2f(v & 0xffffu), a0);
        a1 = fmaf(wt, bf2f(v >> 16), a1);
        a2 = fmaf(wt, bf2f((unsigned int)v2), a2);
    }
    unsigned int* Aw = (unsigned int*)(agg + (size_t)w * IN_CH);
    Aw[lane] = (unsigned int)f2bf(di * a0) | ((unsigned int)f2bf(di * a1) << 16);
    ((unsigned short*)Aw)[128 + lane] = f2bf(di * a2);
}

// ---------------- MFMA GEMM: y_pre = relu(agg @ W1 + b1) @ W2 ----------------
__global__ __launch_bounds__(256, 2) void
k_gemm_mfma(const unsigned short* __restrict__ agg, const unsigned short* __restrict__ W1f,
            const float* __restrict__ b1, const float* __restrict__ W2,
            float* __restrict__ y_pre) {
    __shared__ unsigned short Af[MB * IN_CH];   // 24 KB, fragment-ordered
    __shared__ float red[4][MB][2];             // 2 KB

    int t  = threadIdx.x;
    int m0 = blockIdx.x * MB;

    {
        const uint4* src = (const uint4*)agg;   // 24 chunks per row
        for (int idx = t; idx < MB * 24; idx += 256) {
            int row = idx / 24, c = idx % 24;
            int g = m0 + row;
            uint4 v = make_uint4(0u, 0u, 0u, 0u);
            if (g < N_NODES) v = src[(size_t)g * 24 + c];
            int mt = row >> 4, m = row & 15, kc = c >> 2, q = c & 3;
            ((uint4*)Af)[(mt * 6 + kc) * 64 + q * 16 + m] = v;
        }
    }
    __syncthreads();

    int wid = t >> 6, lane = t & 63;
    int nl = lane & 15, q = lane >> 4;

    float b1v[8], w2a[8], w2b[8];
#pragma unroll
    for (int nt = 0; nt < 8; ++nt) {
        int n = wid * 128 + nt * 16 + nl;
        b1v[nt] = b1[n];
        w2a[nt] = W2[n * 2 + 0];
        w2b[nt] = W2[n * 2 + 1];
    }

    f32x4 acc[4][8];
#pragma unroll
    for (int mt = 0; mt < 4; ++mt)
#pragma unroll
        for (int nt = 0; nt < 8; ++nt) acc[mt][nt] = (f32x4){0.f, 0.f, 0.f, 0.f};

    const bf16x8* Afv = (const bf16x8*)Af;
    const bf16x8* Bv  = (const bf16x8*)W1f;
#pragma unroll
    for (int kc = 0; kc < 6; ++kc) {
        bf16x8 a[4];
#pragma unroll
        for (int mt = 0; mt < 4; ++mt) a[mt] = Afv[(mt * 6 + kc) * 64 + lane];
#pragma unroll
        for (int nt = 0; nt < 8; ++nt) {
            bf16x8 b = Bv[((wid * 8 + nt) * 6 + kc) * 64 + lane];
#pragma unroll
            for (int mt = 0; mt < 4; ++mt)
                acc[mt][nt] = __builtin_amdgcn_mfma_f32_16x16x32_bf16(a[mt], b, acc[mt][nt], 0, 0, 0);
        }
    }

#pragma unroll
    for (int mt = 0; mt < 4; ++mt) {
#pragma unroll
        for (int r = 0; r < 4; ++r) {
            float p0 = 0.f, p1 = 0.f;
#pragma unroll
            for (int nt = 0; nt < 8; ++nt) {
                float h = fmaxf(acc[mt][nt][r] + b1v[nt], 0.f);
                p0 = fmaf(h, w2a[nt], p0);
                p1 = fmaf(h, w2b[nt], p1);
            }
#pragma unroll
            for (int off = 1; off < 16; off <<= 1) {
                p0 += __shfl_xor(p0, off);
                p1 += __shfl_xor(p1, off);
            }
            if (nl == 0) {
                int row = mt * 16 + q * 4 + r;
                red[wid][row][0] = p0;
                red[wid][row][1] = p1;
            }
        }
    }
    __syncthreads();
    if (t < MB * 2) {
        int row = t >> 1, j = t & 1;
        float s = red[0][row][j] + red[1][row][j] + red[2][row][j] + red[3][row][j];
        int g = m0 + row;
        if (g < N_NODES) y_pre[g * 2 + j] = s;
    }
}

// ---------------- layer-2 gather + bias + softmax ----------------
__global__ void k_gather_y(const int* __restrict__ row_start, const int* __restrict__ csr_src,
                           const float* __restrict__ csr_w, const float* __restrict__ dinv,
                           const float* __restrict__ y_pre, const float* __restrict__ b2,
                           float* __restrict__ out) {
    int i = blockIdx.x * blockDim.x + threadIdx.x;
    if (i >= N_NODES) return;
    float di = dinv[i];
    float a0 = di * y_pre[i * 2 + 0];
    float a1 = di * y_pre[i * 2 + 1];
    int jlo = row_start[i], jhi = row_start[i + 1];
    for (int j = jlo; j < jhi; ++j) {
        int   r  = csr_src[j];
        float wt = csr_w[j];
        a0 = fmaf(wt, y_pre[r * 2 + 0], a0);
        a1 = fmaf(wt, y_pre[r * 2 + 1], a1);
    }
    float ya = di * a0 + b2[0];
    float yb = di * a1 + b2[1];
    float mx = fmaxf(ya, yb);
    float e0 = expf(ya - mx);
    float e1 = expf(yb - mx);
    float inv = 1.0f / (e0 + e1);
    out[i * 2 + 0] = e0 * inv;
    out[i * 2 + 1] = e1 * inv;
}

// ---------------- launch ----------------

extern "C" void kernel_launch(void* const* d_in, const int* in_sizes, int n_in,
                              void* d_out, int out_size, void* d_ws, size_t ws_size,
                              hipStream_t stream) {
    const int*   ei = (const int*)d_in[0];
    const float* X  = (const float*)d_in[1];
    const float* uY = (const float*)d_in[2];
    const float* W1 = (const float*)d_in[3];
    const float* b1 = (const float*)d_in[4];
    const float* W2 = (const float*)d_in[5];
    const float* b2 = (const float*)d_in[6];
    float* out = (float*)d_out;

    char* ws = (char*)d_ws;
    auto carve = [&](size_t bytes) {
        char* p = ws;
        ws += (bytes + 255) & ~size_t(255);
        return p;
    };
    int*   cnt       = (int*)carve(N_NODES * sizeof(int));
    int*   bsum      = (int*)carve(NB * sizeof(int));
    int*   bex       = (int*)carve(NB * sizeof(int));
    int*   row_start = (int*)carve((N_NODES + 1) * sizeof(int));
    int*   cursor    = (int*)carve(N_NODES * sizeof(int));
    int*   csr_src   = (int*)carve((size_t)N_EDGES * sizeof(int));
    float* csr_w     = (float*)carve((size_t)N_EDGES * sizeof(float));
    float* dinv      = (float*)carve(N_NODES * sizeof(float));
    unsigned short* latent = (unsigned short*)carve((size_t)N_NODES * IN_CH * 2);
    unsigned short* aggb   = (unsigned short*)carve((size_t)N_NODES * IN_CH * 2);
    unsigned short* W1f    = (unsigned short*)carve((size_t)IN_CH * HID * 2);
    float* y_pre     = (float*)carve((size_t)N_NODES * 2 * sizeof(float));

    k_zero_cnt    <<<cdiv(N_NODES, 256), 256, 0, stream>>>(cnt);
    k_count       <<<cdiv(N_EDGES, 256), 256, 0, stream>>>(ei + N_EDGES, cnt);
    k_block_reduce<<<NB, 256, 0, stream>>>(cnt, bsum);
    k_scan_bsums  <<<1, 256, 0, stream>>>(bsum, bex);
    k_block_scan  <<<NB, 256, 0, stream>>>(cnt, bex, row_start, cursor, dinv);
    k_scatter     <<<cdiv(N_EDGES, 256), 256, 0, stream>>>(ei, dinv, cursor, csr_src, csr_w);

    k_cvt_latent  <<<cdiv(N_NODES * 48, 256), 256, 0, stream>>>(uY, X, latent);
    k_w1_tile     <<<cdiv(IN_CH * HID, 256), 256, 0, stream>>>(W1, W1f);

    k_gather_agg  <<<cdiv(N_NODES, 4), 256, 0, stream>>>(row_start, csr_src, csr_w, dinv, latent, aggb);

    k_gemm_mfma   <<<cdiv(N_NODES, MB), 256, 0, stream>>>(aggb, W1f, b1, W2, y_pre);

    k_gather_y    <<<cdiv(N_NODES, 256), 256, 0, stream>>>(row_start, csr_src, csr_w, dinv, y_pre, b2, out);
}

// Round 6
// 211.825 us; speedup vs baseline: 2.7883x; 1.1001x over previous
//
#include <hip/hip_runtime.h>

#define N_NODES 50000
#define N_EDGES 400000
#define FEATS   128
#define LAT     64
#define IN_CH   192   // LAT + FEATS
#define HID     512
#define MB      64    // GEMM rows per block
#define NB      196   // cdiv(N_NODES, 256)

typedef __attribute__((ext_vector_type(8))) short bf16x8;
typedef __attribute__((ext_vector_type(4))) float f32x4;

static inline int cdiv(int a, int b) { return (a + b - 1) / b; }

__device__ __forceinline__ unsigned short f2bf(float f) {
    unsigned int u = __float_as_uint(f);
    u = (u + 0x7fffu + ((u >> 16) & 1u)) >> 16;   // round-to-nearest-even
    return (unsigned short)u;
}
__device__ __forceinline__ float bf_lo(unsigned int u) {   // low ushort -> float
    return __uint_as_float(u << 16);
}
__device__ __forceinline__ float bf_hi(unsigned int u) {   // high ushort -> float
    return __uint_as_float(u & 0xffff0000u);
}

// ---------------- CSR build ----------------

__global__ void k_count(const int* __restrict__ col, int* __restrict__ cnt) {
    int e = blockIdx.x * blockDim.x + threadIdx.x;
    if (e < N_EDGES) atomicAdd(&cnt[col[e]], 1);
}

__global__ __launch_bounds__(256) void
k_block_reduce(const int* __restrict__ cnt, int* __restrict__ bsum) {
    __shared__ int wsums[4];
    int i = blockIdx.x * 256 + threadIdx.x;
    int v = (i < N_NODES) ? cnt[i] : 0;
#pragma unroll
    for (int off = 32; off; off >>= 1) v += __shfl_down(v, off);
    if ((threadIdx.x & 63) == 0) wsums[threadIdx.x >> 6] = v;
    __syncthreads();
    if (threadIdx.x == 0) bsum[blockIdx.x] = wsums[0] + wsums[1] + wsums[2] + wsums[3];
}

__global__ __launch_bounds__(256) void
k_scan_bsums(const int* __restrict__ bsum, int* __restrict__ bex) {
    __shared__ int wsums[4];
    int t = threadIdx.x, lane = t & 63, wid = t >> 6;
    int v = (t < NB) ? bsum[t] : 0;
    int x = v;
#pragma unroll
    for (int off = 1; off < 64; off <<= 1) {
        int y = __shfl_up(x, off);
        if (lane >= off) x += y;
    }
    if (lane == 63) wsums[wid] = x;
    __syncthreads();
    int wo = 0;
    for (int w = 0; w < wid; ++w) wo += wsums[w];
    if (t < NB) bex[t] = wo + x - v;   // exclusive prefix
}

__global__ __launch_bounds__(256) void
k_block_scan(const int* __restrict__ cnt, const int* __restrict__ bex,
             int* __restrict__ row_start, int* __restrict__ cursor,
             float* __restrict__ dinv) {
    __shared__ int wsums[4];
    int t = threadIdx.x, lane = t & 63, wid = t >> 6;
    int i = blockIdx.x * 256 + t;
    int v = (i < N_NODES) ? cnt[i] : 0;
    int x = v;
#pragma unroll
    for (int off = 1; off < 64; off <<= 1) {
        int y = __shfl_up(x, off);
        if (lane >= off) x += y;
    }
    if (lane == 63) wsums[wid] = x;
    __syncthreads();
    int wo = 0;
    for (int w = 0; w < wid; ++w) wo += wsums[w];
    int ex = bex[blockIdx.x] + wo + x - v;
    if (i < N_NODES) {
        row_start[i] = ex;
        cursor[i]    = ex;
        dinv[i]      = rsqrtf((float)(v + 1));   // +1 self-loop
    }
    if (blockIdx.x == 0 && t == 0) row_start[N_NODES] = N_EDGES;
}

__global__ void k_scatter(const int* __restrict__ ei, int* __restrict__ cursor,
                          int* __restrict__ csr_src) {
    int e = blockIdx.x * blockDim.x + threadIdx.x;
    if (e >= N_EDGES) return;
    int r = ei[e];
    int c = ei[N_EDGES + e];
    int pos = atomicAdd(&cursor[c], 1);
    csr_src[pos] = r;
}

// ---------------- precision conversions ----------------
__global__ void k_cvt_latent(const float* __restrict__ uY, const float* __restrict__ X,
                             unsigned short* __restrict__ latent) {
    int idx = blockIdx.x * blockDim.x + threadIdx.x;   // float4 index, 48/row
    if (idx >= N_NODES * 48) return;
    int i = idx / 48, q = idx % 48;
    const float4* uY4 = (const float4*)uY;
    const float4* X4  = (const float4*)X;
    float4 v = (q < LAT / 4) ? uY4[i * (LAT / 4) + q]
                             : X4[i * (FEATS / 4) + (q - LAT / 4)];
    uint2 o;
    o.x = (unsigned int)f2bf(v.x) | ((unsigned int)f2bf(v.y) << 16);
    o.y = (unsigned int)f2bf(v.z) | ((unsigned int)f2bf(v.w) << 16);
    ((uint2*)latent)[idx] = o;
}

// retile W1 [192,512] fp32 -> fragment-ordered bf16
__global__ void k_w1_tile(const float* __restrict__ W1, unsigned short* __restrict__ W1f) {
    int idx = blockIdx.x * blockDim.x + threadIdx.x;
    if (idx >= IN_CH * HID) return;
    int k = idx / HID, n = idx % HID;       // coalesced read over n
    int ntile = n >> 4, nn = n & 15;
    int kc = k >> 5, q = (k >> 3) & 3, j = k & 7;
    int dst = (((ntile * 6 + kc) * 64 + q * 16 + nn) << 3) + j;
    W1f[dst] = f2bf(W1[idx]);
}

// ---------------- layer-1 gather: 2 edges per wave, uint3 per lane ----------------
// half h = lane>>5 handles edges j = jlo+h, jlo+h+2, ...
// lane covers feats [6l, 6l+6) of its edge via 3 dwords.
__global__ __launch_bounds__(256) void
k_gather_agg(const int* __restrict__ row_start, const int* __restrict__ csr_src,
             const float* __restrict__ dinv,
             const unsigned short* __restrict__ latent, unsigned short* __restrict__ agg) {
    int w    = blockIdx.x * 4 + (threadIdx.x >> 6);
    int lane = threadIdx.x & 63;
    if (w >= N_NODES) return;
    int half = lane >> 5, l = lane & 31;
    int l3 = l * 3;
    const unsigned int* __restrict__ L = (const unsigned int*)latent;

    float di = dinv[w];
    float acc0 = 0.f, acc1 = 0.f, acc2 = 0.f, acc3 = 0.f, acc4 = 0.f, acc5 = 0.f;
    if (half == 0) {
        const unsigned int* p = L + w * 96 + l3;
        unsigned int u0 = p[0], u1 = p[1], u2 = p[2];
        // seed with di * latent[w]; the final store multiplies by di again,
        // completing the self-loop's dinv^2. (Round-5 bug: seeding with di^2
        // made the self term di^3.)
        acc0 = di * bf_lo(u0); acc1 = di * bf_hi(u0);
        acc2 = di * bf_lo(u1); acc3 = di * bf_hi(u1);
        acc4 = di * bf_lo(u2); acc5 = di * bf_hi(u2);
    }

    int jlo = row_start[w], jhi = row_start[w + 1];
    int j = jlo + half;
    int r = (j < jhi) ? csr_src[j] : 0;
    for (; j < jhi; j += 2) {
        int rn = (j + 2 < jhi) ? csr_src[j + 2] : 0;   // prefetch next index
        float wt = dinv[r];
        const unsigned int* p = L + r * 96 + l3;
        unsigned int u0 = p[0], u1 = p[1], u2 = p[2];
        acc0 = fmaf(wt, bf_lo(u0), acc0);
        acc1 = fmaf(wt, bf_hi(u0), acc1);
        acc2 = fmaf(wt, bf_lo(u1), acc2);
        acc3 = fmaf(wt, bf_hi(u1), acc3);
        acc4 = fmaf(wt, bf_lo(u2), acc4);
        acc5 = fmaf(wt, bf_hi(u2), acc5);
        r = rn;
    }

    // combine halves (feature f lives in lanes l and l+32)
    acc0 += __shfl_xor(acc0, 32);
    acc1 += __shfl_xor(acc1, 32);
    acc2 += __shfl_xor(acc2, 32);
    acc3 += __shfl_xor(acc3, 32);
    acc4 += __shfl_xor(acc4, 32);
    acc5 += __shfl_xor(acc5, 32);

    if (half == 0) {
        unsigned int* q = (unsigned int*)agg + w * 96 + l3;
        q[0] = (unsigned int)f2bf(di * acc0) | ((unsigned int)f2bf(di * acc1) << 16);
        q[1] = (unsigned int)f2bf(di * acc2) | ((unsigned int)f2bf(di * acc3) << 16);
        q[2] = (unsigned int)f2bf(di * acc4) | ((unsigned int)f2bf(di * acc5) << 16);
    }
}

// ---------------- MFMA GEMM: y_pre = relu(agg @ W1 + b1) @ W2 ----------------
__global__ __launch_bounds__(256, 2) void
k_gemm_mfma(const unsigned short* __restrict__ agg, const unsigned short* __restrict__ W1f,
            const float* __restrict__ b1, const float* __restrict__ W2,
            float* __restrict__ y_pre) {
    __shared__ unsigned short Af[MB * IN_CH];   // 24 KB, fragment-ordered
    __shared__ float red[4][MB][2];             // 2 KB

    int t  = threadIdx.x;
    int m0 = blockIdx.x * MB;

    {
        const uint4* src = (const uint4*)agg;   // 24 chunks per row
        for (int idx = t; idx < MB * 24; idx += 256) {
            int row = idx / 24, c = idx % 24;
            int g = m0 + row;
            uint4 v = make_uint4(0u, 0u, 0u, 0u);
            if (g < N_NODES) v = src[(size_t)g * 24 + c];
            int mt = row >> 4, m = row & 15, kc = c >> 2, q = c & 3;
            ((uint4*)Af)[(mt * 6 + kc) * 64 + q * 16 + m] = v;
        }
    }
    __syncthreads();

    int wid = t >> 6, lane = t & 63;
    int nl = lane & 15, q = lane >> 4;

    float b1v[8], w2a[8], w2b[8];
#pragma unroll
    for (int nt = 0; nt < 8; ++nt) {
        int n = wid * 128 + nt * 16 + nl;
        b1v[nt] = b1[n];
        w2a[nt] = W2[n * 2 + 0];
        w2b[nt] = W2[n * 2 + 1];
    }

    f32x4 acc[4][8];
#pragma unroll
    for (int mt = 0; mt < 4; ++mt)
#pragma unroll
        for (int nt = 0; nt < 8; ++nt) acc[mt][nt] = (f32x4){0.f, 0.f, 0.f, 0.f};

    const bf16x8* Afv = (const bf16x8*)Af;
    const bf16x8* Bv  = (const bf16x8*)W1f;
#pragma unroll
    for (int kc = 0; kc < 6; ++kc) {
        bf16x8 a[4];
#pragma unroll
        for (int mt = 0; mt < 4; ++mt) a[mt] = Afv[(mt * 6 + kc) * 64 + lane];
#pragma unroll
        for (int nt = 0; nt < 8; ++nt) {
            bf16x8 b = Bv[((wid * 8 + nt) * 6 + kc) * 64 + lane];
#pragma unroll
            for (int mt = 0; mt < 4; ++mt)
                acc[mt][nt] = __builtin_amdgcn_mfma_f32_16x16x32_bf16(a[mt], b, acc[mt][nt], 0, 0, 0);
        }
    }

#pragma unroll
    for (int mt = 0; mt < 4; ++mt) {
#pragma unroll
        for (int r = 0; r < 4; ++r) {
            float p0 = 0.f, p1 = 0.f;
#pragma unroll
            for (int nt = 0; nt < 8; ++nt) {
                float h = fmaxf(acc[mt][nt][r] + b1v[nt], 0.f);
                p0 = fmaf(h, w2a[nt], p0);
                p1 = fmaf(h, w2b[nt], p1);
            }
#pragma unroll
            for (int off = 1; off < 16; off <<= 1) {
                p0 += __shfl_xor(p0, off);
                p1 += __shfl_xor(p1, off);
            }
            if (nl == 0) {
                int row = mt * 16 + q * 4 + r;
                red[wid][row][0] = p0;
                red[wid][row][1] = p1;
            }
        }
    }
    __syncthreads();
    if (t < MB * 2) {
        int row = t >> 1, j = t & 1;
        float s = red[0][row][j] + red[1][row][j] + red[2][row][j] + red[3][row][j];
        int g = m0 + row;
        if (g < N_NODES) y_pre[g * 2 + j] = s;
    }
}

// ---------------- layer-2 gather + bias + softmax ----------------
__global__ void k_gather_y(const int* __restrict__ row_start, const int* __restrict__ csr_src,
                           const float* __restrict__ dinv,
                           const float* __restrict__ y_pre, const float* __restrict__ b2,
                           float* __restrict__ out) {
    int i = blockIdx.x * blockDim.x + threadIdx.x;
    if (i >= N_NODES) return;
    float di = dinv[i];
    float a0 = di * y_pre[i * 2 + 0];
    float a1 = di * y_pre[i * 2 + 1];
    int jlo = row_start[i], jhi = row_start[i + 1];
    for (int j = jlo; j < jhi; ++j) {
        int   r  = csr_src[j];
        float wt = dinv[r];
        a0 = fmaf(wt, y_pre[r * 2 + 0], a0);
        a1 = fmaf(wt, y_pre[r * 2 + 1], a1);
    }
    float ya = di * a0 + b2[0];
    float yb = di * a1 + b2[1];
    float mx = fmaxf(ya, yb);
    float e0 = expf(ya - mx);
    float e1 = expf(yb - mx);
    float inv = 1.0f / (e0 + e1);
    out[i * 2 + 0] = e0 * inv;
    out[i * 2 + 1] = e1 * inv;
}

// ---------------- launch ----------------

extern "C" void kernel_launch(void* const* d_in, const int* in_sizes, int n_in,
                              void* d_out, int out_size, void* d_ws, size_t ws_size,
                              hipStream_t stream) {
    const int*   ei = (const int*)d_in[0];
    const float* X  = (const float*)d_in[1];
    const float* uY = (const float*)d_in[2];
    const float* W1 = (const float*)d_in[3];
    const float* b1 = (const float*)d_in[4];
    const float* W2 = (const float*)d_in[5];
    const float* b2 = (const float*)d_in[6];
    float* out = (float*)d_out;

    char* ws = (char*)d_ws;
    auto carve = [&](size_t bytes) {
        char* p = ws;
        ws += (bytes + 255) & ~size_t(255);
        return p;
    };
    int*   cnt       = (int*)carve(N_NODES * sizeof(int));
    int*   bsum      = (int*)carve(NB * sizeof(int));
    int*   bex       = (int*)carve(NB * sizeof(int));
    int*   row_start = (int*)carve((N_NODES + 1) * sizeof(int));
    int*   cursor    = (int*)carve(N_NODES * sizeof(int));
    int*   csr_src   = (int*)carve((size_t)N_EDGES * sizeof(int));
    float* dinv      = (float*)carve(N_NODES * sizeof(float));
    unsigned short* latent = (unsigned short*)carve((size_t)N_NODES * IN_CH * 2);
    unsigned short* aggb   = (unsigned short*)carve((size_t)N_NODES * IN_CH * 2);
    unsigned short* W1f    = (unsigned short*)carve((size_t)IN_CH * HID * 2);
    float* y_pre     = (float*)carve((size_t)N_NODES * 2 * sizeof(float));

    hipMemsetAsync(cnt, 0, N_NODES * sizeof(int), stream);
    k_count       <<<cdiv(N_EDGES, 256), 256, 0, stream>>>(ei + N_EDGES, cnt);
    k_block_reduce<<<NB, 256, 0, stream>>>(cnt, bsum);
    k_scan_bsums  <<<1, 256, 0, stream>>>(bsum, bex);
    k_block_scan  <<<NB, 256, 0, stream>>>(cnt, bex, row_start, cursor, dinv);
    k_scatter     <<<cdiv(N_EDGES, 256), 256, 0, stream>>>(ei, cursor, csr_src);

    k_cvt_latent  <<<cdiv(N_NODES * 48, 256), 256, 0, stream>>>(uY, X, latent);
    k_w1_tile     <<<cdiv(IN_CH * HID, 256), 256, 0, stream>>>(W1, W1f);

    k_gather_agg  <<<cdiv(N_NODES, 4), 256, 0, stream>>>(row_start, csr_src, dinv, latent, aggb);

    k_gemm_mfma   <<<cdiv(N_NODES, MB), 256, 0, stream>>>(aggb, W1f, b1, W2, y_pre);

    k_gather_y    <<<cdiv(N_NODES, 256), 256, 0, stream>>>(row_start, csr_src, dinv, y_pre, b2, out);
}

// Round 7
// 202.510 us; speedup vs baseline: 2.9166x; 1.0460x over previous
//
#include <hip/hip_runtime.h>

#define N_NODES 50000
#define N_EDGES 400000
#define FEATS   128
#define LAT     64
#define IN_CH   192   // LAT + FEATS
#define HID     512
#define MB      64    // GEMM rows per block
#define NB      196   // cdiv(N_NODES, 256)

#define CNT_BLKS 1563    // cdiv(N_EDGES, 256)
#define CVT_BLKS 9375    // N_NODES*48/256
#define W1_BLKS  384     // IN_CH*HID/256

typedef __attribute__((ext_vector_type(8))) short bf16x8;
typedef __attribute__((ext_vector_type(4))) float f32x4;

static inline int cdiv(int a, int b) { return (a + b - 1) / b; }

__device__ __forceinline__ unsigned short f2bf(float f) {
    unsigned int u = __float_as_uint(f);
    u = (u + 0x7fffu + ((u >> 16) & 1u)) >> 16;   // round-to-nearest-even
    return (unsigned short)u;
}
__device__ __forceinline__ float bf_lo(unsigned int u) {
    return __uint_as_float(u << 16);
}
__device__ __forceinline__ float bf_hi(unsigned int u) {
    return __uint_as_float(u & 0xffff0000u);
}

// ---------------- fused front: edge-count + latent convert + W1 retile ----------------
__global__ __launch_bounds__(256) void
k_front(const int* __restrict__ col, int* __restrict__ cnt,
        const float* __restrict__ uY, const float* __restrict__ X,
        unsigned short* __restrict__ latent,
        const float* __restrict__ W1, unsigned short* __restrict__ W1f) {
    int bid = blockIdx.x;
    if (bid < CNT_BLKS) {
        int e = bid * 256 + threadIdx.x;
        if (e < N_EDGES) atomicAdd(&cnt[col[e]], 1);
    } else if (bid < CNT_BLKS + CVT_BLKS) {
        int idx = (bid - CNT_BLKS) * 256 + threadIdx.x;   // float4 index, 48/row
        int i = idx / 48, q = idx % 48;
        const float4* uY4 = (const float4*)uY;
        const float4* X4  = (const float4*)X;
        float4 v = (q < LAT / 4) ? uY4[i * (LAT / 4) + q]
                                 : X4[i * (FEATS / 4) + (q - LAT / 4)];
        uint2 o;
        o.x = (unsigned int)f2bf(v.x) | ((unsigned int)f2bf(v.y) << 16);
        o.y = (unsigned int)f2bf(v.z) | ((unsigned int)f2bf(v.w) << 16);
        ((uint2*)latent)[idx] = o;
    } else {
        int idx = (bid - CNT_BLKS - CVT_BLKS) * 256 + threadIdx.x;
        if (idx < IN_CH * HID) {
            int k = idx / HID, n = idx % HID;   // coalesced read over n
            int ntile = n >> 4, nn = n & 15;
            int kc = k >> 5, q = (k >> 3) & 3, j = k & 7;
            int dst = (((ntile * 6 + kc) * 64 + q * 16 + nn) << 3) + j;
            W1f[dst] = f2bf(W1[idx]);
        }
    }
}

// ---------------- CSR scan chain ----------------
__global__ __launch_bounds__(256) void
k_block_reduce(const int* __restrict__ cnt, int* __restrict__ bsum) {
    __shared__ int wsums[4];
    int i = blockIdx.x * 256 + threadIdx.x;
    int v = (i < N_NODES) ? cnt[i] : 0;
#pragma unroll
    for (int off = 32; off; off >>= 1) v += __shfl_down(v, off);
    if ((threadIdx.x & 63) == 0) wsums[threadIdx.x >> 6] = v;
    __syncthreads();
    if (threadIdx.x == 0) bsum[blockIdx.x] = wsums[0] + wsums[1] + wsums[2] + wsums[3];
}

__global__ __launch_bounds__(256) void
k_scan_bsums(const int* __restrict__ bsum, int* __restrict__ bex) {
    __shared__ int wsums[4];
    int t = threadIdx.x, lane = t & 63, wid = t >> 6;
    int v = (t < NB) ? bsum[t] : 0;
    int x = v;
#pragma unroll
    for (int off = 1; off < 64; off <<= 1) {
        int y = __shfl_up(x, off);
        if (lane >= off) x += y;
    }
    if (lane == 63) wsums[wid] = x;
    __syncthreads();
    int wo = 0;
    for (int w = 0; w < wid; ++w) wo += wsums[w];
    if (t < NB) bex[t] = wo + x - v;   // exclusive prefix
}

__global__ __launch_bounds__(256) void
k_block_scan(const int* __restrict__ cnt, const int* __restrict__ bex,
             int* __restrict__ row_start, int* __restrict__ cursor,
             float* __restrict__ dinv) {
    __shared__ int wsums[4];
    int t = threadIdx.x, lane = t & 63, wid = t >> 6;
    int i = blockIdx.x * 256 + t;
    int v = (i < N_NODES) ? cnt[i] : 0;
    int x = v;
#pragma unroll
    for (int off = 1; off < 64; off <<= 1) {
        int y = __shfl_up(x, off);
        if (lane >= off) x += y;
    }
    if (lane == 63) wsums[wid] = x;
    __syncthreads();
    int wo = 0;
    for (int w = 0; w < wid; ++w) wo += wsums[w];
    int ex = bex[blockIdx.x] + wo + x - v;
    if (i < N_NODES) {
        row_start[i] = ex;
        cursor[i]    = ex;
        dinv[i]      = rsqrtf((float)(v + 1));   // +1 self-loop
    }
    if (blockIdx.x == 0 && t == 0) row_start[N_NODES] = N_EDGES;
}

__global__ void k_scatter(const int* __restrict__ ei, int* __restrict__ cursor,
                          int* __restrict__ csr_src) {
    int e = blockIdx.x * blockDim.x + threadIdx.x;
    if (e >= N_EDGES) return;
    int r = ei[e];
    int c = ei[N_EDGES + e];
    int pos = atomicAdd(&cursor[c], 1);
    csr_src[pos] = r;
}

// ---------------- layer-1 gather: 4 edges per wave (16 lanes x 6 dwords each) ----
// quarter qt = lane>>4 handles edges j = jlo+qt, jlo+qt+4, ...
// lane covers dwords [6l, 6l+6) of its edge's 96-dword row.
__global__ __launch_bounds__(256) void
k_gather_agg(const int* __restrict__ row_start, const int* __restrict__ csr_src,
             const float* __restrict__ dinv,
             const unsigned short* __restrict__ latent, unsigned short* __restrict__ agg) {
    int w    = blockIdx.x * 4 + (threadIdx.x >> 6);
    int lane = threadIdx.x & 63;
    if (w >= N_NODES) return;
    int qt = lane >> 4, l = lane & 15;
    int c0 = l * 6;
    const unsigned int* __restrict__ L = (const unsigned int*)latent;

    float di = dinv[w];
    float acc[12];
    if (qt == 0) {
        // seed with di * latent[w]; final store multiplies by di again -> dinv^2 self term
        const unsigned int* p = L + w * 96 + c0;
#pragma unroll
        for (int d = 0; d < 6; ++d) {
            unsigned int u = p[d];
            acc[2 * d]     = di * bf_lo(u);
            acc[2 * d + 1] = di * bf_hi(u);
        }
    } else {
#pragma unroll
        for (int d = 0; d < 12; ++d) acc[d] = 0.f;
    }

    int jlo = row_start[w], jhi = row_start[w + 1];
    int j = jlo + qt;
    int r = (j < jhi) ? csr_src[j] : 0;
    for (; j < jhi; j += 4) {
        int rn = (j + 4 < jhi) ? csr_src[j + 4] : 0;   // prefetch next index
        float wt = dinv[r];
        const unsigned int* p = L + r * 96 + c0;
        unsigned int u0 = p[0], u1 = p[1], u2 = p[2], u3 = p[3], u4 = p[4], u5 = p[5];
        acc[0]  = fmaf(wt, bf_lo(u0), acc[0]);
        acc[1]  = fmaf(wt, bf_hi(u0), acc[1]);
        acc[2]  = fmaf(wt, bf_lo(u1), acc[2]);
        acc[3]  = fmaf(wt, bf_hi(u1), acc[3]);
        acc[4]  = fmaf(wt, bf_lo(u2), acc[4]);
        acc[5]  = fmaf(wt, bf_hi(u2), acc[5]);
        acc[6]  = fmaf(wt, bf_lo(u3), acc[6]);
        acc[7]  = fmaf(wt, bf_hi(u3), acc[7]);
        acc[8]  = fmaf(wt, bf_lo(u4), acc[8]);
        acc[9]  = fmaf(wt, bf_hi(u4), acc[9]);
        acc[10] = fmaf(wt, bf_lo(u5), acc[10]);
        acc[11] = fmaf(wt, bf_hi(u5), acc[11]);
        r = rn;
    }

    // combine quarters (feature d lives in lanes l, l+16, l+32, l+48)
#pragma unroll
    for (int d = 0; d < 12; ++d) {
        acc[d] += __shfl_xor(acc[d], 16);
        acc[d] += __shfl_xor(acc[d], 32);
    }

    if (qt == 0) {
        unsigned int* qp = (unsigned int*)agg + w * 96 + c0;
#pragma unroll
        for (int d = 0; d < 6; ++d)
            qp[d] = (unsigned int)f2bf(di * acc[2 * d]) |
                    ((unsigned int)f2bf(di * acc[2 * d + 1]) << 16);
    }
}

// ---------------- MFMA GEMM: y_pre = relu(agg @ W1 + b1) @ W2 ----------------
__global__ __launch_bounds__(256, 2) void
k_gemm_mfma(const unsigned short* __restrict__ agg, const unsigned short* __restrict__ W1f,
            const float* __restrict__ b1, const float* __restrict__ W2,
            float* __restrict__ y_pre) {
    __shared__ unsigned short Af[MB * IN_CH];   // 24 KB, fragment-ordered
    __shared__ float red[4][MB][2];             // 2 KB

    int t  = threadIdx.x;
    int m0 = blockIdx.x * MB;

    {
        const uint4* src = (const uint4*)agg;   // 24 chunks per row
        for (int idx = t; idx < MB * 24; idx += 256) {
            int row = idx / 24, c = idx % 24;
            int g = m0 + row;
            uint4 v = make_uint4(0u, 0u, 0u, 0u);
            if (g < N_NODES) v = src[(size_t)g * 24 + c];
            int mt = row >> 4, m = row & 15, kc = c >> 2, q = c & 3;
            ((uint4*)Af)[(mt * 6 + kc) * 64 + q * 16 + m] = v;
        }
    }
    __syncthreads();

    int wid = t >> 6, lane = t & 63;
    int nl = lane & 15, q = lane >> 4;

    float b1v[8], w2a[8], w2b[8];
#pragma unroll
    for (int nt = 0; nt < 8; ++nt) {
        int n = wid * 128 + nt * 16 + nl;
        b1v[nt] = b1[n];
        w2a[nt] = W2[n * 2 + 0];
        w2b[nt] = W2[n * 2 + 1];
    }

    f32x4 acc[4][8];
#pragma unroll
    for (int mt = 0; mt < 4; ++mt)
#pragma unroll
        for (int nt = 0; nt < 8; ++nt) acc[mt][nt] = (f32x4){0.f, 0.f, 0.f, 0.f};

    const bf16x8* Afv = (const bf16x8*)Af;
    const bf16x8* Bv  = (const bf16x8*)W1f;
#pragma unroll
    for (int kc = 0; kc < 6; ++kc) {
        bf16x8 a[4];
#pragma unroll
        for (int mt = 0; mt < 4; ++mt) a[mt] = Afv[(mt * 6 + kc) * 64 + lane];
#pragma unroll
        for (int nt = 0; nt < 8; ++nt) {
            bf16x8 b = Bv[((wid * 8 + nt) * 6 + kc) * 64 + lane];
#pragma unroll
            for (int mt = 0; mt < 4; ++mt)
                acc[mt][nt] = __builtin_amdgcn_mfma_f32_16x16x32_bf16(a[mt], b, acc[mt][nt], 0, 0, 0);
        }
    }

#pragma unroll
    for (int mt = 0; mt < 4; ++mt) {
#pragma unroll
        for (int r = 0; r < 4; ++r) {
            float p0 = 0.f, p1 = 0.f;
#pragma unroll
            for (int nt = 0; nt < 8; ++nt) {
                float h = fmaxf(acc[mt][nt][r] + b1v[nt], 0.f);
                p0 = fmaf(h, w2a[nt], p0);
                p1 = fmaf(h, w2b[nt], p1);
            }
#pragma unroll
            for (int off = 1; off < 16; off <<= 1) {
                p0 += __shfl_xor(p0, off);
                p1 += __shfl_xor(p1, off);
            }
            if (nl == 0) {
                int row = mt * 16 + q * 4 + r;
                red[wid][row][0] = p0;
                red[wid][row][1] = p1;
            }
        }
    }
    __syncthreads();
    if (t < MB * 2) {
        int row = t >> 1, j = t & 1;
        float s = red[0][row][j] + red[1][row][j] + red[2][row][j] + red[3][row][j];
        int g = m0 + row;
        if (g < N_NODES) y_pre[g * 2 + j] = s;
    }
}

// ---------------- layer-2 gather + softmax: 8 lanes per node ----------------
__global__ __launch_bounds__(256) void
k_gather_y(const int* __restrict__ row_start, const int* __restrict__ csr_src,
           const float* __restrict__ dinv,
           const float* __restrict__ y_pre, const float* __restrict__ b2,
           float* __restrict__ out) {
    int i  = blockIdx.x * 32 + (threadIdx.x >> 3);
    int l8 = threadIdx.x & 7;
    if (i >= N_NODES) return;
    float di = dinv[i];
    float a0 = 0.f, a1 = 0.f;
    if (l8 == 0) {
        a0 = di * y_pre[i * 2 + 0];
        a1 = di * y_pre[i * 2 + 1];
    }
    int jlo = row_start[i], jhi = row_start[i + 1];
    for (int j = jlo + l8; j < jhi; j += 8) {
        int   r  = csr_src[j];
        float wt = dinv[r];
        a0 = fmaf(wt, y_pre[r * 2 + 0], a0);
        a1 = fmaf(wt, y_pre[r * 2 + 1], a1);
    }
#pragma unroll
    for (int off = 1; off < 8; off <<= 1) {
        a0 += __shfl_xor(a0, off);
        a1 += __shfl_xor(a1, off);
    }
    if (l8 == 0) {
        float ya = di * a0 + b2[0];
        float yb = di * a1 + b2[1];
        float mx = fmaxf(ya, yb);
        float e0 = expf(ya - mx);
        float e1 = expf(yb - mx);
        float inv = 1.0f / (e0 + e1);
        out[i * 2 + 0] = e0 * inv;
        out[i * 2 + 1] = e1 * inv;
    }
}

// ---------------- launch ----------------

extern "C" void kernel_launch(void* const* d_in, const int* in_sizes, int n_in,
                              void* d_out, int out_size, void* d_ws, size_t ws_size,
                              hipStream_t stream) {
    const int*   ei = (const int*)d_in[0];
    const float* X  = (const float*)d_in[1];
    const float* uY = (const float*)d_in[2];
    const float* W1 = (const float*)d_in[3];
    const float* b1 = (const float*)d_in[4];
    const float* W2 = (const float*)d_in[5];
    const float* b2 = (const float*)d_in[6];
    float* out = (float*)d_out;

    char* ws = (char*)d_ws;
    auto carve = [&](size_t bytes) {
        char* p = ws;
        ws += (bytes + 255) & ~size_t(255);
        return p;
    };
    int*   cnt       = (int*)carve(N_NODES * sizeof(int));
    int*   bsum      = (int*)carve(NB * sizeof(int));
    int*   bex       = (int*)carve(NB * sizeof(int));
    int*   row_start = (int*)carve((N_NODES + 1) * sizeof(int));
    int*   cursor    = (int*)carve(N_NODES * sizeof(int));
    int*   csr_src   = (int*)carve((size_t)N_EDGES * sizeof(int));
    float* dinv      = (float*)carve(N_NODES * sizeof(float));
    unsigned short* latent = (unsigned short*)carve((size_t)N_NODES * IN_CH * 2);
    unsigned short* aggb   = (unsigned short*)carve((size_t)N_NODES * IN_CH * 2);
    unsigned short* W1f    = (unsigned short*)carve((size_t)IN_CH * HID * 2);
    float* y_pre     = (float*)carve((size_t)N_NODES * 2 * sizeof(float));

    hipMemsetAsync(cnt, 0, N_NODES * sizeof(int), stream);
    k_front       <<<CNT_BLKS + CVT_BLKS + W1_BLKS, 256, 0, stream>>>(
                        ei + N_EDGES, cnt, uY, X, latent, W1, W1f);
    k_block_reduce<<<NB, 256, 0, stream>>>(cnt, bsum);
    k_scan_bsums  <<<1, 256, 0, stream>>>(bsum, bex);
    k_block_scan  <<<NB, 256, 0, stream>>>(cnt, bex, row_start, cursor, dinv);
    k_scatter     <<<cdiv(N_EDGES, 256), 256, 0, stream>>>(ei, cursor, csr_src);

    k_gather_agg  <<<cdiv(N_NODES, 4), 256, 0, stream>>>(row_start, csr_src, dinv, latent, aggb);

    k_gemm_mfma   <<<cdiv(N_NODES, MB), 256, 0, stream>>>(aggb, W1f, b1, W2, y_pre);

    k_gather_y    <<<cdiv(N_NODES, 32), 256, 0, stream>>>(row_start, csr_src, dinv, y_pre, b2, out);
}